// Round 9
// baseline (296.820 us; speedup 1.0000x reference)
//
#include <hip/hip_runtime.h>

// ChromaSelfAttention on MI355X (gfx950).
// Pipeline: cvt x->f16 | transpose-cvt W->W^T f16 | QKV GEMM + output GEMM
//           (shared BK=32 deep-pipeline template, 2 blocks/CU, counted vmcnt,
//           T1 XCD swizzle, 64B-row swizzle, T5 setprio) | transpose V |
//           flash attention (8 waves x 16 q-rows, swapped QK^T, register P,
//           dbuf LDS, defer-max, XCD swizzle).
// fp16 operands, fp32 accumulation. Softmax scale*log2(e) folded into Q projection.

typedef _Float16 f16;
typedef __attribute__((ext_vector_type(8))) _Float16 f16x8;
typedef __attribute__((ext_vector_type(4))) _Float16 f16x4;
typedef __attribute__((ext_vector_type(4))) float f32x4;
typedef __attribute__((ext_vector_type(4))) unsigned int u32x4;

#define QSCALE (0.08838834764831845f * 1.4426950408889634f)  // d^-0.5 * log2(e)
#define SWZ3(r) (((r) & 3) | (((r) >> 1) & 4))  // attn K-tile swizzle (256B rows)
#define SWZV(r) ((r) & 7)                       // attn V-tile swizzle (128B rows)
#define SWZG(r) (((r) >> 1) & 3)                // GEMM 64B-row swizzle (2-way = free)

static __device__ __forceinline__ void gload16(void* lds, const void* g) {
  __builtin_amdgcn_global_load_lds(
      (__attribute__((address_space(1))) void*)g,
      (__attribute__((address_space(3))) void*)lds, 16, 0, 0);
}

// ---------------- fp32 -> fp16 conversion of x_q/x_k/x_v (z selects) -------
__global__ __launch_bounds__(256) void cvt_x_kernel(
    const float* __restrict__ x0, const float* __restrict__ x1,
    const float* __restrict__ x2, f16* __restrict__ out) {
  const float* x = blockIdx.z == 0 ? x0 : (blockIdx.z == 1 ? x1 : x2);
  f16* o = out + (size_t)blockIdx.z * 8388608;
  size_t i = ((size_t)blockIdx.x * 256 + threadIdx.x) * 8;
  f32x4 a = *(const f32x4*)(x + i);
  f32x4 b = *(const f32x4*)(x + i + 4);
  f16x8 r;
  r[0] = (f16)a[0]; r[1] = (f16)a[1]; r[2] = (f16)a[2]; r[3] = (f16)a[3];
  r[4] = (f16)b[0]; r[5] = (f16)b[1]; r[6] = (f16)b[2]; r[7] = (f16)b[3];
  *(f16x8*)(o + i) = r;
}

// -------- W [K=2048][N=2048] f32 -> W^T [N][K] f16 (z: Wq,Wk,Wv,Wo) --------
__global__ __launch_bounds__(256) void cvt_w_kernel(
    const float* __restrict__ w0, const float* __restrict__ w1,
    const float* __restrict__ w2, const float* __restrict__ w3,
    f16* __restrict__ out) {
  const float* W = blockIdx.z == 0 ? w0 : blockIdx.z == 1 ? w1
                 : blockIdx.z == 2 ? w2 : w3;
  f16* WT = out + (size_t)blockIdx.z * 4194304;
  __shared__ f16 tile[64][68];  // +4 pad
  const int tx = threadIdx.x & 15, ty = threadIdx.x >> 4;
  const int k0 = blockIdx.y * 64, n0 = blockIdx.x * 64;
#pragma unroll
  for (int i = 0; i < 4; ++i) {
    int r = ty + i * 16;  // local k
    f32x4 v = *(const f32x4*)(W + (size_t)(k0 + r) * 2048 + n0 + tx * 4);
    tile[r][tx * 4 + 0] = (f16)v[0]; tile[r][tx * 4 + 1] = (f16)v[1];
    tile[r][tx * 4 + 2] = (f16)v[2]; tile[r][tx * 4 + 3] = (f16)v[3];
  }
  __syncthreads();
#pragma unroll
  for (int i = 0; i < 4; ++i) {
    int n = ty + i * 16;  // local n
    f16x4 o;
    o[0] = tile[tx * 4 + 0][n]; o[1] = tile[tx * 4 + 1][n];
    o[2] = tile[tx * 4 + 2][n]; o[3] = tile[tx * 4 + 3][n];
    *(f16x4*)(WT + (size_t)(n0 + n) * 2048 + k0 + tx * 4) = o;
  }
}

// ---------------- shared BK=32 GEMM template -------------------------------
// C = A[M,2048] @ Bt[2048,*]^T. BK=32, 64 K-tiles, 8 waves (2M x 4N).
// MODE 0 (QKV): BM=128, BN=256, per-wave 64x64 (acc[4][4]); LDS 48KB dbuf ->
//   2 blocks/CU; grid 768. Epilogue: head-split f16 [b,h,l,d] + bias (+QSCALE z0).
// MODE 1 (out): BM=128, BN=128, per-wave 64x32 (acc[4][2]); LDS 32KB dbuf;
//   grid 512 = exactly 2/CU, 1 round. Epilogue: f32 [4096,2048] + bias.
// Per K-tile: {stage t+1 (NLOADS gloads), vmcnt(NLOADS) [t landed, t+1 in
// flight - never drains], barrier}, {8/6 ds_read, lgkm, 16/8 MFMA}, barrier.
// 64B-row swizzle byte^=SWZG(row)<<4 (8 bank-quads per 16-lane group, free).
// 2 blocks/CU co-residency fills vmcnt/barrier stalls with the other block's MFMA.
template <int MODE>
__global__ __launch_bounds__(512, 4) void gemm128_kernel(
    const f16* __restrict__ Abase, const f16* __restrict__ Btbase,
    void* __restrict__ Obase, const float* __restrict__ b0,
    const float* __restrict__ b1, const float* __restrict__ b2) {
  constexpr int BN = MODE == 0 ? 256 : 128;       // N tile
  constexpr int NJ = MODE == 0 ? 4 : 2;           // B frags per wave
  constexpr int NSPAN = MODE == 0 ? 64 : 32;      // per-wave N span
  constexpr int BLOADS = MODE == 0 ? 2 : 1;       // B gloads per thread
  constexpr int BUFSZ = 8192 + BN * 64;           // A 8KB + B tile bytes
  const int lid = blockIdx.x;
  int bn, bm, z;
  if (MODE == 0) {
    const int logi = (lid & 7) * 96 + (lid >> 3);  // bijective, 768%8==0
    bn = logi & 7; bm = (logi >> 3) & 31; z = logi >> 8;
  } else {
    const int logi = (lid & 7) * 64 + (lid >> 3);  // bijective, 512%8==0
    bn = logi & 15; bm = logi >> 4; z = 0;
  }
  const f16* A  = Abase  + (size_t)z * 8388608;
  const f16* Bt = Btbase + (size_t)z * 4194304;
  const float* bias = z == 0 ? b0 : (z == 1 ? b1 : b2);
  const float qsc = (MODE == 0 && z == 0) ? QSCALE : 1.0f;
  const int tid = threadIdx.x, lane = tid & 63, w = tid >> 6;  // 8 waves
  const int wm = w >> 2, wn = w & 3;
  const int l15 = lane & 15, lg = lane >> 4;
  __shared__ alignas(16) char smb[2 * BUFSZ];

  f32x4 acc[4][NJ];
#pragma unroll
  for (int i = 0; i < 4; ++i)
#pragma unroll
    for (int j = 0; j < NJ; ++j) acc[i][j] = (f32x4)0.f;

#define GSTAGE(KT, C_)                                                        \
  {                                                                           \
    char* Ab_ = smb + (C_) * BUFSZ;                                           \
    char* Bb_ = Ab_ + 8192;                                                   \
    {                                                                         \
      int L = tid * 16;                                                       \
      int row = L >> 6, pcol = L & 63;                                        \
      int scol = pcol ^ (SWZG(row) << 4);                                     \
      gload16(Ab_ + L,                                                        \
              (const char*)A + ((size_t)(bm * 128 + row) * 2048 + (KT) * 32) * 2 + scol); \
    }                                                                         \
    _Pragma("unroll") for (int p = 0; p < BLOADS; ++p) {                      \
      int L = p * 8192 + tid * 16;                                            \
      int row = L >> 6, pcol = L & 63;                                        \
      int scol = pcol ^ (SWZG(row) << 4);                                     \
      gload16(Bb_ + L,                                                        \
              (const char*)Bt + ((size_t)(bn * BN + row) * 2048 + (KT) * 32) * 2 + scol); \
    }                                                                         \
  }

  GSTAGE(0, 0);
#pragma unroll 1
  for (int kt = 0; kt < 64; ++kt) {
    const int c = kt & 1;
    if (kt < 63) {
      GSTAGE(kt + 1, c ^ 1);  // issue first: these stay in flight across tile
      if constexpr (MODE == 0)
        asm volatile("s_waitcnt vmcnt(3)" ::: "memory");  // tile kt's 3 landed
      else
        asm volatile("s_waitcnt vmcnt(2)" ::: "memory");
    } else {
      asm volatile("s_waitcnt vmcnt(0)" ::: "memory");
    }
    __builtin_amdgcn_s_barrier();  // tile kt visible to all waves

    const char* Ab = smb + c * BUFSZ;
    const char* Bb = Ab + 8192;
    f16x8 af[4], bf[NJ];
#pragma unroll
    for (int i = 0; i < 4; ++i) {
      int row = wm * 64 + i * 16 + l15;
      af[i] = *(const f16x8*)(Ab + row * 64 + ((lg * 16) ^ (SWZG(row) << 4)));
    }
#pragma unroll
    for (int j = 0; j < NJ; ++j) {
      int row = wn * NSPAN + j * 16 + l15;
      bf[j] = *(const f16x8*)(Bb + row * 64 + ((lg * 16) ^ (SWZG(row) << 4)));
    }
    asm volatile("s_waitcnt lgkmcnt(0)" ::: "memory");
    __builtin_amdgcn_sched_barrier(0);
    __builtin_amdgcn_s_setprio(1);
#pragma unroll
    for (int i = 0; i < 4; ++i)
#pragma unroll
      for (int j = 0; j < NJ; ++j)
        acc[i][j] = __builtin_amdgcn_mfma_f32_16x16x32_f16(af[i], bf[j], acc[i][j], 0, 0, 0);
    __builtin_amdgcn_s_setprio(0);
    __builtin_amdgcn_sched_barrier(0);
    __builtin_amdgcn_s_barrier();  // all waves done reading buf c (WAR guard)
  }

  // epilogue
  if (MODE == 0) {
    f16* Oz = (f16*)Obase + (size_t)z * 8388608;
#pragma unroll
    for (int i = 0; i < 4; ++i)
#pragma unroll
      for (int j = 0; j < NJ; ++j) {
        int col = bn * BN + wn * NSPAN + j * 16 + l15;
        int h = col >> 7, d = col & 127;
        float bv = bias[col];
#pragma unroll
        for (int r = 0; r < 4; ++r) {
          int rowg = bm * 128 + wm * 64 + i * 16 + lg * 4 + r;
          int b_ = rowg >> 11, lpos = rowg & 2047;
          Oz[(size_t)(b_ * 16 + h) * 262144 + (size_t)lpos * 128 + d] =
              (f16)((acc[i][j][r] + bv) * qsc);
        }
      }
  } else {
    float* Out = (float*)Obase;
#pragma unroll
    for (int i = 0; i < 4; ++i)
#pragma unroll
      for (int j = 0; j < NJ; ++j) {
        int col = bn * BN + wn * NSPAN + j * 16 + l15;
        float bv = bias[col];
#pragma unroll
        for (int r = 0; r < 4; ++r) {
          int rowg = bm * 128 + wm * 64 + i * 16 + lg * 4 + r;
          Out[(size_t)rowg * 2048 + col] = acc[i][j][r] + bv;
        }
      }
  }
#undef GSTAGE
}

// ---------------- V [b,h,l,128] -> V^T [b,h,128,L] (f16) -------------------
__global__ __launch_bounds__(256) void tr_v_kernel(const f16* __restrict__ v,
                                                   f16* __restrict__ vtout) {
  const int bh = blockIdx.z;
  const f16* V = v + (size_t)bh * 262144;
  f16* VT = vtout + (size_t)bh * 262144;
  __shared__ f16 tile[64][68];
  const int tx = threadIdx.x & 15, ty = threadIdx.x >> 4;
  const int l0 = blockIdx.x * 64, d0 = blockIdx.y * 64;
#pragma unroll
  for (int i = 0; i < 4; ++i) {
    int r = ty + i * 16;  // local l
    f16x4 val = *(const f16x4*)(V + (size_t)(l0 + r) * 128 + d0 + tx * 4);
    tile[r][tx * 4 + 0] = val[0]; tile[r][tx * 4 + 1] = val[1];
    tile[r][tx * 4 + 2] = val[2]; tile[r][tx * 4 + 3] = val[3];
  }
  __syncthreads();
#pragma unroll
  for (int i = 0; i < 4; ++i) {
    int d = ty + i * 16;  // local d
    f16x4 o;
    o[0] = tile[tx * 4 + 0][d]; o[1] = tile[tx * 4 + 1][d];
    o[2] = tile[tx * 4 + 2][d]; o[3] = tile[tx * 4 + 3][d];
    *(f16x4*)(VT + (size_t)(d0 + d) * 2048 + l0 + tx * 4) = o;
  }
}

// ---------------- flash attention v5 (8 waves x 16 q-rows) -----------------
// 512 threads, KVBLK=64, double-buffered K/V LDS (64KB), 1 barrier/tile.
// 2 blocks/CU x 8 waves = 4 waves/SIMD (latency hiding).
// Swapped QK^T: S = mfma(K,Q), lane owns q-row l15; K rows permuted so packed
// P lands directly in PV's A-fragment (zero shuffle). Defer-max THR=8.
// XCD-chunked block swizzle: 4 bh per XCD -> K/V stay in that XCD's L2.
__global__ __launch_bounds__(512, 4) void attn_kernel(
    const f16* __restrict__ q, const f16* __restrict__ k,
    const f16* __restrict__ vt, f16* __restrict__ o) {
  const int orig = blockIdx.y * 16 + blockIdx.x;      // [0,512)
  const int swz = (orig & 7) * 64 + (orig >> 3);      // bijective (512%8==0)
  const int qt = swz & 15, bh = swz >> 4;
  const int tid = threadIdx.x, lane = tid & 63, w = tid >> 6;  // w in [0,8)
  const int l15 = lane & 15, lg = lane >> 4;
  const f16* Qb = q + (size_t)bh * 262144 + (size_t)qt * 128 * 128;
  const char* Kb = (const char*)(k + (size_t)bh * 262144);
  const char* Vtb = (const char*)(vt + (size_t)bh * 262144);
  __shared__ alignas(16) char sm[65536];  // buf b: K @ b*32768 (16K), V @ +16384 (16K)

  // Q fragments (B-operand): wave w owns q-rows w*16+l15; k = ks*32+lg*8(+0..7)
  f16x8 qf[4];
#pragma unroll
  for (int ks = 0; ks < 4; ++ks)
    qf[ks] = *(const f16x8*)(Qb + (w * 16 + l15) * 128 + ks * 32 + lg * 8);

  f32x4 oacc[8];
#pragma unroll
  for (int df = 0; df < 8; ++df) oacc[df] = (f32x4)0.f;
  float mrow = -1e30f, ps = 0.f;
  const int rA = ((l15 >> 2) << 3) + (l15 & 3);  // K-frag row permutation base

#define STAGE(T, B)                                                          \
  {                                                                          \
    char* Ks_ = sm + (B) * 32768;                                            \
    char* Vs_ = Ks_ + 16384;                                                 \
    _Pragma("unroll") for (int i = 0; i < 2; ++i) {                          \
      int c = i * 8 + w;                                                     \
      int phys = c * 1024 + lane * 16;                                       \
      {                                                                      \
        int row = phys >> 8, pcol = phys & 255;                              \
        int lcol = pcol ^ (SWZ3(row) << 4);                                  \
        gload16(Ks_ + c * 1024, Kb + (size_t)((T) * 64 + row) * 256 + lcol); \
      }                                                                      \
      {                                                                      \
        int row = phys >> 7, pcol = phys & 127;                              \
        int lcol = pcol ^ (SWZV(row) << 4);                                  \
        gload16(Vs_ + c * 1024, Vtb + (size_t)row * 4096 + (T) * 128 + lcol);\
      }                                                                      \
    }                                                                        \
  }

  STAGE(0, 0);
  int cur = 0;
  for (int t = 0; t < 32; ++t) {
    __syncthreads();  // drains own vmcnt: buf[cur] staged; all waves done with buf[cur^1]
    if (t < 31) STAGE(t + 1, cur ^ 1);  // overlaps with compute below
    const char* Ks = sm + cur * 32768;
    const char* Vs = Ks + 16384;

    // ---- QK^T swapped: s[nf] = S[kv'][q] -----------------------------------
    f32x4 s[4];
#pragma unroll
    for (int nf = 0; nf < 4; ++nf) s[nf] = (f32x4)0.f;
    __builtin_amdgcn_s_setprio(1);
#pragma unroll
    for (int ks = 0; ks < 4; ++ks) {
      f16x8 kf[4];
#pragma unroll
      for (int nf = 0; nf < 4; ++nf) {
        int row = ((nf & 1) << 5) + ((nf >> 1) << 2) + rA;  // permuted kv row
        int colb = (ks * 64 + lg * 16) ^ (SWZ3(row) << 4);
        kf[nf] = *(const f16x8*)(Ks + row * 256 + colb);
      }
#pragma unroll
      for (int nf = 0; nf < 4; ++nf)
        s[nf] = __builtin_amdgcn_mfma_f32_16x16x32_f16(kf[nf], qf[ks], s[nf], 0, 0, 0);
    }
    __builtin_amdgcn_s_setprio(0);
    // lane (l15,lg) reg r of s[nf] = S[kv=(nf&1)*32+lg*8+(nf>>1)*4+r][q-row l15]
    // (log2 units: QSCALE folded into Q)

    // ---- online softmax (defer-max), P packed in registers -----------------
    unsigned int pk[2][4];  // [kvs][word] -> PV A-frag direct
    {
      float m0 = fmaxf(fmaxf(s[0][0], s[0][1]), fmaxf(s[0][2], s[0][3]));
      float m1 = fmaxf(fmaxf(s[1][0], s[1][1]), fmaxf(s[1][2], s[1][3]));
      float m2 = fmaxf(fmaxf(s[2][0], s[2][1]), fmaxf(s[2][2], s[2][3]));
      float m3 = fmaxf(fmaxf(s[3][0], s[3][1]), fmaxf(s[3][2], s[3][3]));
      float mx = fmaxf(fmaxf(m0, m1), fmaxf(m2, m3));
      mx = fmaxf(mx, __shfl_xor(mx, 16));
      mx = fmaxf(mx, __shfl_xor(mx, 32));
      if (!__all(mx <= mrow + 8.f)) {  // rare after first tile
        float mnew = fmaxf(mrow, mx);
        float sc = exp2f(mrow - mnew);
        mrow = mnew;
        ps *= sc;
#pragma unroll
        for (int r = 0; r < 4; ++r) {
          float scr = __shfl(sc, (lane & 48) | (lg * 4 + r));
#pragma unroll
          for (int df = 0; df < 8; ++df) oacc[df][r] *= scr;
        }
      }
      float m = mrow;
      float psum = 0.f;
#pragma unroll
      for (int nf = 0; nf < 4; ++nf)
#pragma unroll
        for (int h = 0; h < 2; ++h) {
          float p0 = exp2f(s[nf][2 * h] - m);
          float p1 = exp2f(s[nf][2 * h + 1] - m);
          psum += p0 + p1;
          pk[nf & 1][(nf >> 1) * 2 + h] =
              __builtin_bit_cast(unsigned int, __builtin_amdgcn_cvt_pkrtz(p0, p1));
        }
      ps += psum;  // cross-lane reduction deferred to epilogue
    }

    // ---- PV: oacc += P[16 x 64] @ V[64 x 128] ------------------------------
    __builtin_amdgcn_s_setprio(1);
#pragma unroll
    for (int kvs = 0; kvs < 2; ++kvs) {
      f16x8 pa = __builtin_bit_cast(f16x8, *(const u32x4*)pk[kvs]);
#pragma unroll
      for (int df = 0; df < 8; ++df) {
        int row = df * 16 + l15;
        int colb = (kvs * 64 + lg * 16) ^ (SWZV(row) << 4);
        f16x8 vb = *(const f16x8*)(Vs + row * 128 + colb);
        oacc[df] = __builtin_amdgcn_mfma_f32_16x16x32_f16(pa, vb, oacc[df], 0, 0, 0);
      }
    }
    __builtin_amdgcn_s_setprio(0);
    cur ^= 1;
  }

  // epilogue: reduce l across lanes, normalize, write o [b,l,h*128+d] f16
  const int b_ = bh >> 4, h_ = bh & 15;
  f16* Ob = o + (size_t)b_ * 4194304 + (size_t)qt * 128 * 2048 + h_ * 128;
  float lr = ps;
  lr += __shfl_xor(lr, 16);
  lr += __shfl_xor(lr, 32);
  float inv = 1.f / lr;  // for q-row l15
#pragma unroll
  for (int r = 0; r < 4; ++r) {
    float invr = __shfl(inv, (lane & 48) | (lg * 4 + r));
    int rl = w * 16 + lg * 4 + r;
#pragma unroll
    for (int df = 0; df < 8; ++df)
      Ob[(size_t)rl * 2048 + df * 16 + l15] = (f16)(oacc[df][r] * invr);
  }
#undef STAGE
}

// ---------------------------------------------------------------------------
extern "C" void kernel_launch(void* const* d_in, const int* in_sizes, int n_in,
                              void* d_out, int out_size, void* d_ws, size_t ws_size,
                              hipStream_t stream) {
  const float* xq = (const float*)d_in[0];
  const float* xk = (const float*)d_in[1];
  const float* xv = (const float*)d_in[2];
  const float* Wq = (const float*)d_in[3];
  const float* bq = (const float*)d_in[4];
  const float* Wk = (const float*)d_in[5];
  const float* bk = (const float*)d_in[6];
  const float* Wv = (const float*)d_in[7];
  const float* bv = (const float*)d_in[8];
  const float* Wo = (const float*)d_in[9];
  const float* bo = (const float*)d_in[10];

  // ws layout (bytes), total 128 MiB:
  //   [0,50331648)        xh: x_q/x_k/x_v f16 (3 x 16 MiB)
  //   [50331648,83886080) wt: WqT/WkT/WvT/WoT f16 (4 x 8 MiB)
  //   [83886080,134217728) qkv: q/k/v head-split f16 (3 x 16 MiB)
  //   vT aliases xh_q slot (dead after QKV GEMM); o aliases xh_k slot.
  char* ws = (char*)d_ws;
  f16* xh   = (f16*)(ws);
  f16* wt   = (f16*)(ws + 50331648);
  f16* qkv  = (f16*)(ws + 83886080);
  f16* vtb  = (f16*)(ws);             // alias: x_q f16 region
  f16* oatt = (f16*)(ws + 16777216);  // alias: x_k f16 region
  float* outp = (float*)d_out;

  hipLaunchKernelGGL(cvt_x_kernel, dim3(4096, 1, 3), dim3(256), 0, stream,
                     xq, xk, xv, xh);
  hipLaunchKernelGGL(cvt_w_kernel, dim3(32, 32, 4), dim3(256), 0, stream,
                     Wq, Wk, Wv, Wo, wt);
  hipLaunchKernelGGL((gemm128_kernel<0>), dim3(768), dim3(512), 0, stream,
                     xh, wt, (void*)qkv, bq, bk, bv);
  hipLaunchKernelGGL(tr_v_kernel, dim3(32, 2, 32), dim3(256), 0, stream,
                     qkv + (size_t)2 * 8388608, vtb);
  hipLaunchKernelGGL(attn_kernel, dim3(16, 32), dim3(512), 0, stream,
                     qkv, qkv + (size_t)8388608, vtb, oatt);
  hipLaunchKernelGGL((gemm128_kernel<1>), dim3(512), dim3(512), 0, stream,
                     oatt, wt + (size_t)3 * 4194304, (void*)outp, bo, bo, bo);
}